// Round 1
// baseline (193.209 us; speedup 1.0000x reference)
//
#include <hip/hip_runtime.h>
#include <hip/hip_bf16.h>

#define DIMS 64

// ---------------------------------------------------------------------------
// Kernel A: XW = X @ W  (into workspace)  and  out = X @ W1  (residual init)
// Block = 256 threads (4 waves). Tile = 64 rows.
//  - W, W1 staged to LDS once (16 KB each).
//  - X tile staged to LDS transposed (Xs[k][row], row-dim padded to 68 so the
//    per-k float4 row reads are 16B-aligned and bank-conflict-light).
//  - Each thread: 4 rows x 4 dims x 2 matrices of fp32 accumulators (32 VGPRs),
//    inner loop k: 3x ds_read_b128 feeding 32 v_fma_f32.
// ---------------------------------------------------------------------------
__global__ __launch_bounds__(256) void gcn_gemm2(
    const float* __restrict__ X, const float* __restrict__ W,
    const float* __restrict__ W1, float* __restrict__ XW,
    float* __restrict__ out, int N)
{
    __shared__ float Ws[64 * 64];
    __shared__ float W1s[64 * 64];
    __shared__ float Xs[64 * 68];   // transposed: Xs[k*68 + row]

    const int t = threadIdx.x;

    // Stage W and W1 (1024 float4 each; 256 threads x 4 iters)
    for (int i = t; i < 1024; i += 256) {
        reinterpret_cast<float4*>(Ws)[i]  = reinterpret_cast<const float4*>(W)[i];
        reinterpret_cast<float4*>(W1s)[i] = reinterpret_cast<const float4*>(W1)[i];
    }

    const int row0 = blockIdx.x * 64;

    // Stage X tile, transposed into LDS. Coalesced float4 global reads.
    for (int i = t; i < 1024; i += 256) {
        const int r  = i >> 4;          // 0..63 tile row
        const int k4 = (i & 15) * 4;    // 0..60 k base
        const int row = row0 + r;
        float4 v = make_float4(0.f, 0.f, 0.f, 0.f);
        if (row < N)
            v = reinterpret_cast<const float4*>(X)[(size_t)row * 16 + (i & 15)];
        Xs[(k4 + 0) * 68 + r] = v.x;
        Xs[(k4 + 1) * 68 + r] = v.y;
        Xs[(k4 + 2) * 68 + r] = v.z;
        Xs[(k4 + 3) * 68 + r] = v.w;
    }
    __syncthreads();

    const int dg = t & 15;   // dim group: dims [4*dg, 4*dg+4)
    const int rg = t >> 4;   // row group: rows [4*rg, 4*rg+4)

    float4 acc[4];
    float4 acc1[4];
    #pragma unroll
    for (int r = 0; r < 4; ++r) {
        acc[r]  = make_float4(0.f, 0.f, 0.f, 0.f);
        acc1[r] = make_float4(0.f, 0.f, 0.f, 0.f);
    }

    #pragma unroll 4
    for (int k = 0; k < 64; ++k) {
        const float4 x4 = *reinterpret_cast<const float4*>(&Xs[k * 68 + rg * 4]);
        const float4 w  = *reinterpret_cast<const float4*>(&Ws[k * 64 + dg * 4]);
        const float4 w1 = *reinterpret_cast<const float4*>(&W1s[k * 64 + dg * 4]);
        const float xr[4] = {x4.x, x4.y, x4.z, x4.w};
        #pragma unroll
        for (int r = 0; r < 4; ++r) {
            acc[r].x  += xr[r] * w.x;  acc[r].y  += xr[r] * w.y;
            acc[r].z  += xr[r] * w.z;  acc[r].w  += xr[r] * w.w;
            acc1[r].x += xr[r] * w1.x; acc1[r].y += xr[r] * w1.y;
            acc1[r].z += xr[r] * w1.z; acc1[r].w += xr[r] * w1.w;
        }
    }

    #pragma unroll
    for (int r = 0; r < 4; ++r) {
        const int row = row0 + rg * 4 + r;
        if (row < N) {
            reinterpret_cast<float4*>(XW)[(size_t)row * 16 + dg]  = acc[r];
            reinterpret_cast<float4*>(out)[(size_t)row * 16 + dg] = acc1[r];
        }
    }
}

// ---------------------------------------------------------------------------
// Kernel B: segmented SpMM scatter. row_ids sorted -> one wave owns EW
// contiguous edges; lane = feature dim. Register-accumulate runs of equal
// destination row; flush via atomicAdd scaled by 1/dd1[row] at boundaries.
// Gathers batched 16-deep for memory-level parallelism.
// ---------------------------------------------------------------------------
#define EDGES_PER_WAVE 512
#define BATCH 16

__global__ __launch_bounds__(256) void gcn_spmm(
    const float* __restrict__ XW, const float* __restrict__ dd1,
    const int* __restrict__ rows, const int* __restrict__ cols,
    float* __restrict__ out, int E)
{
    const int gid  = blockIdx.x * blockDim.x + threadIdx.x;
    const int wave = gid >> 6;
    const int lane = gid & 63;

    const long e0 = (long)wave * EDGES_PER_WAVE;
    if (e0 >= E) return;
    const long e1 = (e0 + EDGES_PER_WAVE < (long)E) ? e0 + EDGES_PER_WAVE : (long)E;

    int cur = rows[e0];     // wave-uniform
    float acc = 0.f;

    for (long base = e0; base < e1; base += BATCH) {
        float v[BATCH];
        int   rr[BATCH];
        // Phase 1: issue all index loads + gathers (16 independent loads in flight)
        #pragma unroll
        for (int j = 0; j < BATCH; ++j) {
            const long ee = base + j;
            const bool valid = (ee < e1);
            const long es = valid ? ee : (e1 - 1);
            const int c = cols[es];
            rr[j] = rows[es];                         // invalid -> rows[e1-1] (== cur by then, no flush)
            v[j]  = XW[(size_t)c * DIMS + lane];      // coalesced 256B row gather
            if (!valid) v[j] = 0.f;
        }
        // Phase 2: segmented accumulate (branches are wave-uniform)
        #pragma unroll
        for (int j = 0; j < BATCH; ++j) {
            const int r = rr[j];
            if (r != cur) {
                const float s = 1.0f / dd1[cur];
                atomicAdd(&out[(size_t)cur * DIMS + lane], acc * s);
                acc = 0.f;
                cur = r;
            }
            acc += v[j];
        }
    }
    const float s = 1.0f / dd1[cur];
    atomicAdd(&out[(size_t)cur * DIMS + lane], acc * s);
}

// ---------------------------------------------------------------------------
extern "C" void kernel_launch(void* const* d_in, const int* in_sizes, int n_in,
                              void* d_out, int out_size, void* d_ws, size_t ws_size,
                              hipStream_t stream) {
    const float* X   = (const float*)d_in[0];
    const float* W   = (const float*)d_in[1];
    const float* W1  = (const float*)d_in[2];
    const float* dd1 = (const float*)d_in[3];
    const int* rows  = (const int*)d_in[4];
    const int* cols  = (const int*)d_in[5];

    const int N = in_sizes[3];       // dd1 has N elements
    const int E = in_sizes[4];       // row_ids count

    float* XW  = (float*)d_ws;       // N*64 fp32 = 25.6 MB scratch
    float* out = (float*)d_out;

    // Kernel A: XW = X@W (ws), out = X@W1 (residual init). Must precede B.
    const int gA = (N + 63) / 64;
    hipLaunchKernelGGL(gcn_gemm2, dim3(gA), dim3(256), 0, stream,
                       X, W, W1, XW, out, N);

    // Kernel B: segmented scatter-add of XW rows into out, scaled by 1/dd1.
    const int waves  = (E + EDGES_PER_WAVE - 1) / EDGES_PER_WAVE;
    const int gB     = (waves + 3) / 4;    // 4 waves per 256-thread block
    hipLaunchKernelGGL(gcn_spmm, dim3(gB), dim3(256), 0, stream,
                       XW, dd1, rows, cols, out, E);
}

// Round 2
// 173.037 us; speedup vs baseline: 1.1166x; 1.1166x over previous
//
#include <hip/hip_runtime.h>
#include <hip/hip_bf16.h>

#define DIMS 64

// ---------------------------------------------------------------------------
// Kernel A: XWh = bf16(X @ W)  (into workspace)  and  out = X @ W1 (fp32)
// Block = 256 threads (4 waves). Tile = 64 rows.
//  - W, W1 staged to LDS once; X tile staged transposed (pad 68).
//  - Each thread: 4 rows x 4 dims x 2 matrices fp32 accumulators.
//  - XW stored as bf16 (halves SpMM gather bytes; threshold headroom is 31x).
// ---------------------------------------------------------------------------
__global__ __launch_bounds__(256) void gcn_gemm2(
    const float* __restrict__ X, const float* __restrict__ W,
    const float* __restrict__ W1, __hip_bfloat16* __restrict__ XWh,
    float* __restrict__ out, int N)
{
    __shared__ float Ws[64 * 64];
    __shared__ float W1s[64 * 64];
    __shared__ float Xs[64 * 68];   // transposed: Xs[k*68 + row]

    const int t = threadIdx.x;

    for (int i = t; i < 1024; i += 256) {
        reinterpret_cast<float4*>(Ws)[i]  = reinterpret_cast<const float4*>(W)[i];
        reinterpret_cast<float4*>(W1s)[i] = reinterpret_cast<const float4*>(W1)[i];
    }

    const int row0 = blockIdx.x * 64;

    for (int i = t; i < 1024; i += 256) {
        const int r  = i >> 4;
        const int k4 = (i & 15) * 4;
        const int row = row0 + r;
        float4 v = make_float4(0.f, 0.f, 0.f, 0.f);
        if (row < N)
            v = reinterpret_cast<const float4*>(X)[(size_t)row * 16 + (i & 15)];
        Xs[(k4 + 0) * 68 + r] = v.x;
        Xs[(k4 + 1) * 68 + r] = v.y;
        Xs[(k4 + 2) * 68 + r] = v.z;
        Xs[(k4 + 3) * 68 + r] = v.w;
    }
    __syncthreads();

    const int dg = t & 15;   // dims [4*dg, 4*dg+4)
    const int rg = t >> 4;   // rows [4*rg, 4*rg+4)

    float4 acc[4];
    float4 acc1[4];
    #pragma unroll
    for (int r = 0; r < 4; ++r) {
        acc[r]  = make_float4(0.f, 0.f, 0.f, 0.f);
        acc1[r] = make_float4(0.f, 0.f, 0.f, 0.f);
    }

    #pragma unroll 4
    for (int k = 0; k < 64; ++k) {
        const float4 x4 = *reinterpret_cast<const float4*>(&Xs[k * 68 + rg * 4]);
        const float4 w  = *reinterpret_cast<const float4*>(&Ws[k * 64 + dg * 4]);
        const float4 w1 = *reinterpret_cast<const float4*>(&W1s[k * 64 + dg * 4]);
        const float xr[4] = {x4.x, x4.y, x4.z, x4.w};
        #pragma unroll
        for (int r = 0; r < 4; ++r) {
            acc[r].x  += xr[r] * w.x;  acc[r].y  += xr[r] * w.y;
            acc[r].z  += xr[r] * w.z;  acc[r].w  += xr[r] * w.w;
            acc1[r].x += xr[r] * w1.x; acc1[r].y += xr[r] * w1.y;
            acc1[r].z += xr[r] * w1.z; acc1[r].w += xr[r] * w1.w;
        }
    }

    #pragma unroll
    for (int r = 0; r < 4; ++r) {
        const int row = row0 + rg * 4 + r;
        if (row < N) {
            reinterpret_cast<float4*>(out)[(size_t)row * 16 + dg] = acc1[r];
            // pack 4 fp32 -> 4 bf16 (8 B), coalesced: row stride = 16 uint2
            uint2 pk;
            __hip_bfloat16* ph = reinterpret_cast<__hip_bfloat16*>(&pk);
            ph[0] = __float2bfloat16(acc[r].x);
            ph[1] = __float2bfloat16(acc[r].y);
            ph[2] = __float2bfloat16(acc[r].z);
            ph[3] = __float2bfloat16(acc[r].w);
            reinterpret_cast<uint2*>(XWh)[(size_t)row * 16 + dg] = pk;
        }
    }
}

// ---------------------------------------------------------------------------
// Kernel B: segmented SpMM scatter over sorted row_ids.
//  - wave owns EDGES_PER_WAVE contiguous edges; lane = feature dim.
//  - bf16 gather rows (128 B/row), fp32 accumulate, atomicAdd flush at
//    segment boundaries scaled by 1/dd1[row].
//  - indices loaded cooperatively (lane j loads idx base+j, __shfl broadcast).
// ---------------------------------------------------------------------------
#define EDGES_PER_WAVE 256
#define BATCH 16

__global__ __launch_bounds__(256) void gcn_spmm(
    const __hip_bfloat16* __restrict__ XWh, const float* __restrict__ dd1,
    const int* __restrict__ rows, const int* __restrict__ cols,
    float* __restrict__ out, int E)
{
    const int gid  = blockIdx.x * blockDim.x + threadIdx.x;
    const int wave = gid >> 6;
    const int lane = gid & 63;

    const long e0 = (long)wave * EDGES_PER_WAVE;
    if (e0 >= E) return;
    const long e1 = (e0 + EDGES_PER_WAVE < (long)E) ? e0 + EDGES_PER_WAVE : (long)E;

    int cur = rows[e0];     // wave-uniform
    float acc = 0.f;

    for (long base = e0; base < e1; base += BATCH) {
        // cooperative index load: lane j holds rows/cols[base + (lane&15)]
        const long il = base + (lane & 15);
        const long ic = (il < e1) ? il : (e1 - 1);
        const int rl = rows[ic];
        const int cl = cols[ic];

        float v[BATCH];
        int   rr[BATCH];
        #pragma unroll
        for (int j = 0; j < BATCH; ++j) {
            const int c = __shfl(cl, j);
            rr[j] = __shfl(rl, j);
            const bool valid = (base + j < e1);
            float x = __bfloat162float(XWh[(size_t)c * DIMS + lane]);
            v[j] = valid ? x : 0.f;
        }
        #pragma unroll
        for (int j = 0; j < BATCH; ++j) {
            const int r = rr[j];
            if (r != cur) {   // wave-uniform branch
                const float s = 1.0f / dd1[cur];
                atomicAdd(&out[(size_t)cur * DIMS + lane], acc * s);
                acc = 0.f;
                cur = r;
            }
            acc += v[j];
        }
    }
    const float s = 1.0f / dd1[cur];
    atomicAdd(&out[(size_t)cur * DIMS + lane], acc * s);
}

// ---------------------------------------------------------------------------
extern "C" void kernel_launch(void* const* d_in, const int* in_sizes, int n_in,
                              void* d_out, int out_size, void* d_ws, size_t ws_size,
                              hipStream_t stream) {
    const float* X   = (const float*)d_in[0];
    const float* W   = (const float*)d_in[1];
    const float* W1  = (const float*)d_in[2];
    const float* dd1 = (const float*)d_in[3];
    const int* rows  = (const int*)d_in[4];
    const int* cols  = (const int*)d_in[5];

    const int N = in_sizes[3];
    const int E = in_sizes[4];

    __hip_bfloat16* XWh = (__hip_bfloat16*)d_ws;   // N*64 bf16 = 12.8 MB
    float* out = (float*)d_out;

    const int gA = (N + 63) / 64;
    hipLaunchKernelGGL(gcn_gemm2, dim3(gA), dim3(256), 0, stream,
                       X, W, W1, XWh, out, N);

    const int waves = (E + EDGES_PER_WAVE - 1) / EDGES_PER_WAVE;
    const int gB    = (waves + 3) / 4;
    hipLaunchKernelGGL(gcn_spmm, dim3(gB), dim3(256), 0, stream,
                       XWh, dd1, rows, cols, out, E);
}

// Round 3
// 148.510 us; speedup vs baseline: 1.3010x; 1.1651x over previous
//
#include <hip/hip_runtime.h>
#include <hip/hip_bf16.h>

#define DIMS 64

// ---------------------------------------------------------------------------
// Kernel A: XWh = bf16(X @ W)  (workspace)  and  out = X @ W1 (fp32 residual)
// Unchanged from round 2: 64-row tile, W/W1/X^T in LDS, 4x4x2 register tile.
// ---------------------------------------------------------------------------
__global__ __launch_bounds__(256) void gcn_gemm2(
    const float* __restrict__ X, const float* __restrict__ W,
    const float* __restrict__ W1, __hip_bfloat16* __restrict__ XWh,
    float* __restrict__ out, int N)
{
    __shared__ float Ws[64 * 64];
    __shared__ float W1s[64 * 64];
    __shared__ float Xs[64 * 68];

    const int t = threadIdx.x;

    for (int i = t; i < 1024; i += 256) {
        reinterpret_cast<float4*>(Ws)[i]  = reinterpret_cast<const float4*>(W)[i];
        reinterpret_cast<float4*>(W1s)[i] = reinterpret_cast<const float4*>(W1)[i];
    }

    const int row0 = blockIdx.x * 64;

    for (int i = t; i < 1024; i += 256) {
        const int r  = i >> 4;
        const int k4 = (i & 15) * 4;
        const int row = row0 + r;
        float4 v = make_float4(0.f, 0.f, 0.f, 0.f);
        if (row < N)
            v = reinterpret_cast<const float4*>(X)[(size_t)row * 16 + (i & 15)];
        Xs[(k4 + 0) * 68 + r] = v.x;
        Xs[(k4 + 1) * 68 + r] = v.y;
        Xs[(k4 + 2) * 68 + r] = v.z;
        Xs[(k4 + 3) * 68 + r] = v.w;
    }
    __syncthreads();

    const int dg = t & 15;
    const int rg = t >> 4;

    float4 acc[4];
    float4 acc1[4];
    #pragma unroll
    for (int r = 0; r < 4; ++r) {
        acc[r]  = make_float4(0.f, 0.f, 0.f, 0.f);
        acc1[r] = make_float4(0.f, 0.f, 0.f, 0.f);
    }

    #pragma unroll 4
    for (int k = 0; k < 64; ++k) {
        const float4 x4 = *reinterpret_cast<const float4*>(&Xs[k * 68 + rg * 4]);
        const float4 w  = *reinterpret_cast<const float4*>(&Ws[k * 64 + dg * 4]);
        const float4 w1 = *reinterpret_cast<const float4*>(&W1s[k * 64 + dg * 4]);
        const float xr[4] = {x4.x, x4.y, x4.z, x4.w};
        #pragma unroll
        for (int r = 0; r < 4; ++r) {
            acc[r].x  += xr[r] * w.x;  acc[r].y  += xr[r] * w.y;
            acc[r].z  += xr[r] * w.z;  acc[r].w  += xr[r] * w.w;
            acc1[r].x += xr[r] * w1.x; acc1[r].y += xr[r] * w1.y;
            acc1[r].z += xr[r] * w1.z; acc1[r].w += xr[r] * w1.w;
        }
    }

    #pragma unroll
    for (int r = 0; r < 4; ++r) {
        const int row = row0 + rg * 4 + r;
        if (row < N) {
            reinterpret_cast<float4*>(out)[(size_t)row * 16 + dg] = acc1[r];
            uint2 pk;
            __hip_bfloat16* ph = reinterpret_cast<__hip_bfloat16*>(&pk);
            ph[0] = __float2bfloat16(acc[r].x);
            ph[1] = __float2bfloat16(acc[r].y);
            ph[2] = __float2bfloat16(acc[r].z);
            ph[3] = __float2bfloat16(acc[r].w);
            reinterpret_cast<uint2*>(XWh)[(size_t)row * 16 + dg] = pk;
        }
    }
}

// ---------------------------------------------------------------------------
// Kernel R: row_ptr[r] = first edge e with rows[e] >= r  (rows sorted).
// ptr has N+1 entries; ptr[N] = E.
// ---------------------------------------------------------------------------
__global__ __launch_bounds__(256) void build_row_ptr(
    const int* __restrict__ rows, int* __restrict__ ptr, int E, int N)
{
    const int e = blockIdx.x * 256 + threadIdx.x;
    if (e >= E) return;
    const int r1 = rows[e];
    const int r0 = (e == 0) ? -1 : rows[e - 1];
    for (int r = r0 + 1; r <= r1; ++r) ptr[r] = e;      // covers gaps (rare)
    if (e == E - 1) {
        for (int r = r1 + 1; r <= N; ++r) ptr[r] = E;
    }
}

// ---------------------------------------------------------------------------
// Kernel B: CSR row-centric aggregation. One wave = 8 destination rows;
// each 8-lane group owns one row. lane d = dims [8d, 8d+8) as bf16x8 (16 B).
//  - global_load_dwordx4 gathers: ONE wave instruction = 8 edges' rows.
//  - No atomics, no shuffles: group-private fp32 acc, one RMW store on top
//    of the X@W1 residual gemm already wrote.
//  - 4-deep edge batch per group -> 32 gathers in flight per wave.
// ---------------------------------------------------------------------------
__global__ __launch_bounds__(256) void gcn_csr(
    const __hip_bfloat16* __restrict__ XWh, const float* __restrict__ dd1,
    const int* __restrict__ ptr, const int* __restrict__ cols,
    float* __restrict__ out, int N, int E)
{
    const int t    = blockIdx.x * 256 + threadIdx.x;
    const int wave = t >> 6;
    const int lane = threadIdx.x & 63;
    const int g    = lane >> 3;     // group 0..7  -> row
    const int d    = lane & 7;      // dim block   -> dims [8d, 8d+8)

    const int row = wave * 8 + g;
    int p0 = 0, p1 = 0;
    if (row < N) { p0 = ptr[row]; p1 = ptr[row + 1]; }

    float2 acc[4];
    #pragma unroll
    for (int k = 0; k < 4; ++k) acc[k] = make_float2(0.f, 0.f);

    for (int e = p0; __any(e < p1); e += 4) {
        uint4 raw[4];
        #pragma unroll
        for (int j = 0; j < 4; ++j) {
            const int  ee  = e + j;
            const bool act = (ee < p1);
            const int  ec  = act ? ee : 0;           // safe index
            const int  c   = cols[ec];               // uniform within group
            raw[j] = make_uint4(0u, 0u, 0u, 0u);
            if (act)
                raw[j] = *reinterpret_cast<const uint4*>(
                    XWh + (((size_t)c) << 6) + (d << 3));
        }
        #pragma unroll
        for (int j = 0; j < 4; ++j) {
            const uint32_t w0 = raw[j].x, w1 = raw[j].y, w2 = raw[j].z, w3 = raw[j].w;
            acc[0].x += __uint_as_float(w0 << 16);
            acc[0].y += __uint_as_float(w0 & 0xffff0000u);
            acc[1].x += __uint_as_float(w1 << 16);
            acc[1].y += __uint_as_float(w1 & 0xffff0000u);
            acc[2].x += __uint_as_float(w2 << 16);
            acc[2].y += __uint_as_float(w2 & 0xffff0000u);
            acc[3].x += __uint_as_float(w3 << 16);
            acc[3].y += __uint_as_float(w3 & 0xffff0000u);
        }
    }

    if (row < N) {
        const float s = 1.0f / dd1[row];
        float4* po = reinterpret_cast<float4*>(out + (size_t)row * DIMS + d * 8);
        float4 o0 = po[0];
        float4 o1 = po[1];
        o0.x += acc[0].x * s;  o0.y += acc[0].y * s;
        o0.z += acc[1].x * s;  o0.w += acc[1].y * s;
        o1.x += acc[2].x * s;  o1.y += acc[2].y * s;
        o1.z += acc[3].x * s;  o1.w += acc[3].y * s;
        po[0] = o0;
        po[1] = o1;
    }
}

// ---------------------------------------------------------------------------
extern "C" void kernel_launch(void* const* d_in, const int* in_sizes, int n_in,
                              void* d_out, int out_size, void* d_ws, size_t ws_size,
                              hipStream_t stream) {
    const float* X   = (const float*)d_in[0];
    const float* W   = (const float*)d_in[1];
    const float* W1  = (const float*)d_in[2];
    const float* dd1 = (const float*)d_in[3];
    const int* rows  = (const int*)d_in[4];
    const int* cols  = (const int*)d_in[5];

    const int N = in_sizes[3];
    const int E = in_sizes[4];

    __hip_bfloat16* XWh = (__hip_bfloat16*)d_ws;                  // N*64 bf16
    size_t ptr_off = (((size_t)N * DIMS * sizeof(__hip_bfloat16)) + 255) & ~(size_t)255;
    int* row_ptr = (int*)((char*)d_ws + ptr_off);                  // N+1 ints

    float* out = (float*)d_out;

    // R: row_ptr from sorted rows (independent of A; tiny)
    hipLaunchKernelGGL(build_row_ptr, dim3((E + 255) / 256), dim3(256), 0, stream,
                       rows, row_ptr, E, N);

    // A: XWh = bf16(X@W), out = X@W1
    hipLaunchKernelGGL(gcn_gemm2, dim3((N + 63) / 64), dim3(256), 0, stream,
                       X, W, W1, XWh, out, N);

    // B: out[row] += (sum_{e in row} XWh[cols[e]]) / dd1[row]
    const int waves  = (N + 7) / 8;
    const int blocks = (waves + 3) / 4;
    hipLaunchKernelGGL(gcn_csr, dim3(blocks), dim3(256), 0, stream,
                       XWh, dd1, row_ptr, cols, out, N, E);
}